// Round 3
// baseline (179.891 us; speedup 1.0000x reference)
//
#include <hip/hip_runtime.h>
#include <hip/hip_bf16.h>
#include <math.h>

// Problem constants
#define B_ 512
#define L_ 256
#define D_ 256
#define V_ 100000
#define O_ 1000

typedef __attribute__((ext_vector_type(8))) short short8;
typedef __attribute__((ext_vector_type(4))) float f32x4;

static __device__ __forceinline__ unsigned short f2bf(float f) {
    union { float f; unsigned u; } v; v.f = f;
    unsigned r = v.u + 0x7FFFu + ((v.u >> 16) & 1u);   // RNE (inputs are finite)
    return (unsigned short)(r >> 16);
}
static __device__ __forceinline__ float bf2f(unsigned short u) {
    union { unsigned u; float f; } v; v.u = ((unsigned)u) << 16;
    return v.f;
}

// ---------------- Kernel 1: embedding gather + cast to bf16 ----------------
__global__ __launch_bounds__(256) void k_gather(const int* __restrict__ tok,
                                                const float* __restrict__ emb,
                                                unsigned short* __restrict__ E) {
    int gid = blockIdx.x * 256 + threadIdx.x;     // 4,194,304 threads
    int row = gid >> 5;                            // 32 threads per 256-elem row
    int off = (gid & 31) << 3;
    int t = tok[row];
    const float4* src = (const float4*)(emb + (size_t)t * D_ + off);
    float4 a = src[0], b = src[1];
    short8 o;
    o[0] = (short)f2bf(a.x); o[1] = (short)f2bf(a.y);
    o[2] = (short)f2bf(a.z); o[3] = (short)f2bf(a.w);
    o[4] = (short)f2bf(b.x); o[5] = (short)f2bf(b.y);
    o[6] = (short)f2bf(b.z); o[7] = (short)f2bf(b.w);
    *(short8*)(E + (size_t)row * D_ + off) = o;
}

// ---------------- Kernel 1b: W_b cast to bf16 (row-major) ----------------
__global__ __launch_bounds__(256) void k_wt(const float* __restrict__ Wb,
                                            unsigned short* __restrict__ Wbf) {
    int i = blockIdx.x * 256 + threadIdx.x;       // 65536
    Wbf[i] = f2bf(Wb[i]);
}

// ---------------- Kernel 2 (fused): per-batch G = E_b * W_b * E_b^T ----------------
// One block per batch, 1024 threads (16 waves, 4 waves/SIMD), 1 block/CU.
// Phase 1: H'[i][j] = sum_e Wb[i,e]*E_b[j,e]  -> store bf16 TRANSPOSED: Ht[j][i],
//          XOR-swizzled (byte ^= (row&7)<<4 within 512B rows).
// Phase 2: G[l][m] = sum_d E_b[l,d]*Ht[m,d]; rowmax over m on the fly.
// Then tanh (monotone) -> softmax over L -> f_w = a^T E_b.
__global__ __launch_bounds__(1024, 4) void k_attn(const unsigned short* __restrict__ E,
                                                  const unsigned short* __restrict__ Wbf,
                                                  float* __restrict__ fw) {
    __shared__ char HtS[131072];          // 256 rows x 512B (bf16), swizzled
    __shared__ float red2[4][256];
    __shared__ float scratch[16];
    int b = blockIdx.x;
    int tid = threadIdx.x;
    int wid = tid >> 6, ln = tid & 63;
    int l16 = ln & 15, gp = ln >> 4;
    const unsigned short* Eb = E + ((size_t)b << 16);

    // ---- Phase 1: 16 waves = 4 (i) x 4 (j), each 64x64 output ----
    {
        int i0 = (wid >> 2) * 64;          // H' row block (Wb rows)
        int j0 = (wid & 3) * 64;           // H' col block (E rows)
        f32x4 acc[4][4] = {};
        for (int k0 = 0; k0 < 256; k0 += 32) {
            int kk = k0 + gp * 8;
            short8 afr[4], bfr[4];
#pragma unroll
            for (int rf = 0; rf < 4; rf++)
                afr[rf] = *(const short8*)(Wbf + ((i0 + rf * 16 + l16) << 8) + kk);
#pragma unroll
            for (int cf = 0; cf < 4; cf++)
                bfr[cf] = *(const short8*)(Eb + ((j0 + cf * 16 + l16) << 8) + kk);
#pragma unroll
            for (int rf = 0; rf < 4; rf++)
#pragma unroll
                for (int cf = 0; cf < 4; cf++)
                    acc[rf][cf] = __builtin_amdgcn_mfma_f32_16x16x32_bf16(
                        afr[rf], bfr[cf], acc[rf][cf], 0, 0, 0);
        }
        // write H' transposed into Ht (bf16), 8B per lane per tile
#pragma unroll
        for (int rf = 0; rf < 4; rf++)
#pragma unroll
            for (int cf = 0; cf < 4; cf++) {
                int i = i0 + rf * 16 + gp * 4;              // H' row -> Ht col
                int j = j0 + cf * 16 + l16;                 // H' col -> Ht row
                unsigned long long pk;
                unsigned short* p = (unsigned short*)&pk;
                p[0] = f2bf(acc[rf][cf][0]);
                p[1] = f2bf(acc[rf][cf][1]);
                p[2] = f2bf(acc[rf][cf][2]);
                p[3] = f2bf(acc[rf][cf][3]);
                int byte = j * 512 + ((i * 2) ^ ((j & 7) << 4));
                *(unsigned long long*)(HtS + byte) = pk;
            }
    }
    __syncthreads();

    // ---- Phase 2: 16 waves = 4 (l) x 4 (m), each 64x64; rowmax on the fly ----
    {
        int l0 = (wid >> 2) * 64;          // G rows
        int m0 = (wid & 3) * 64;           // G cols
        f32x4 acc[4][4] = {};
        for (int k0 = 0; k0 < 256; k0 += 32) {
            int kk = k0 + gp * 8;
            short8 a[4], bb[4];
#pragma unroll
            for (int rf = 0; rf < 4; rf++)
                a[rf] = *(const short8*)(Eb + ((l0 + rf * 16 + l16) << 8) + kk);
#pragma unroll
            for (int cf = 0; cf < 4; cf++) {
                int m = m0 + cf * 16 + l16;
                int byte = m * 512 + ((kk * 2) ^ ((m & 7) << 4));
                bb[cf] = *(const short8*)(HtS + byte);
            }
#pragma unroll
            for (int rf = 0; rf < 4; rf++)
#pragma unroll
                for (int cf = 0; cf < 4; cf++)
                    acc[rf][cf] = __builtin_amdgcn_mfma_f32_16x16x32_bf16(
                        a[rf], bb[cf], acc[rf][cf], 0, 0, 0);
        }
#pragma unroll
        for (int rf = 0; rf < 4; rf++)
#pragma unroll
            for (int r = 0; r < 4; r++) {
                float mx = fmaxf(fmaxf(acc[rf][0][r], acc[rf][1][r]),
                                 fmaxf(acc[rf][2][r], acc[rf][3][r]));
                mx = fmaxf(mx, __shfl_xor(mx, 1));
                mx = fmaxf(mx, __shfl_xor(mx, 2));
                mx = fmaxf(mx, __shfl_xor(mx, 4));
                mx = fmaxf(mx, __shfl_xor(mx, 8));
                if (l16 == 0)
                    red2[wid & 3][l0 + rf * 16 + gp * 4 + r] = mx;
            }
    }
    __syncthreads();

    // ---- tanh + softmax over the 256 row-maxima (first 4 waves carry the data) ----
    float x = -1e30f;
    if (tid < 256)
        x = tanhf(fmaxf(fmaxf(red2[0][tid], red2[1][tid]),
                        fmaxf(red2[2][tid], red2[3][tid])));
    float m = x;
#pragma unroll
    for (int s = 1; s < 64; s <<= 1) m = fmaxf(m, __shfl_xor(m, s));
    if (ln == 0 && wid < 4) scratch[wid] = m;
    __syncthreads();
    float bm = fmaxf(fmaxf(scratch[0], scratch[1]), fmaxf(scratch[2], scratch[3]));
    float e = (tid < 256) ? expf(x - bm) : 0.f;
    float sm = e;
#pragma unroll
    for (int s = 1; s < 64; s <<= 1) sm += __shfl_xor(sm, s);
    if (ln == 0 && wid < 4) scratch[8 + wid] = sm;
    __syncthreads();
    float tot = (scratch[8] + scratch[9]) + (scratch[10] + scratch[11]);
    if (tid < 256) red2[0][tid] = e / tot;   // aq
    __syncthreads();

    // ---- f_w[d] = sum_l aq[l] * E_b[l][d]  (reuse HtS as reduction buffer) ----
    float* fred = (float*)HtS;               // 32 x 256 floats (32KB)
    {
        int g = tid >> 5;                    // 0..31 -> l-range [8g, 8g+8)
        int d0 = (tid & 31) << 3;            // 8 d's per thread
        float s0[8] = {0.f, 0.f, 0.f, 0.f, 0.f, 0.f, 0.f, 0.f};
        int lbase = g << 3;
#pragma unroll
        for (int li = 0; li < 8; li++) {
            int l = lbase + li;
            float aql = red2[0][l];
            short8 v = *(const short8*)(Eb + (l << 8) + d0);
#pragma unroll
            for (int jj = 0; jj < 8; jj++)
                s0[jj] += aql * bf2f((unsigned short)v[jj]);
        }
        f32x4 w0, w1;
        w0[0] = s0[0]; w0[1] = s0[1]; w0[2] = s0[2]; w0[3] = s0[3];
        w1[0] = s0[4]; w1[1] = s0[5]; w1[2] = s0[6]; w1[3] = s0[7];
        *(f32x4*)(fred + g * 256 + d0) = w0;
        *(f32x4*)(fred + g * 256 + d0 + 4) = w1;
    }
    __syncthreads();
    if (tid < 256) {
        float f = 0.f;
#pragma unroll
        for (int g2 = 0; g2 < 32; g2++) f += fred[g2 * 256 + tid];
        fw[(b << 8) + tid] = f;
    }
}

// ---------------- Kernel 3: out = f_w @ lin_w^T + lin_b  (fp32 tiled GEMM) ----------------
__global__ __launch_bounds__(256) void k_out(const float* __restrict__ fw,
                                             const float* __restrict__ lw,
                                             const float* __restrict__ lb,
                                             float* __restrict__ out) {
    __shared__ float As[64][65];
    __shared__ float Bs[64][65];
    int tx = threadIdx.x & 15, ty = threadIdx.x >> 4;
    int r0 = blockIdx.y * 64, n0 = blockIdx.x * 64;
    float acc[4][4] = {};
    for (int k0 = 0; k0 < 256; k0 += 64) {
        __syncthreads();
#pragma unroll
        for (int it = 0; it < 16; it++) {
            int idx = it * 256 + threadIdx.x;
            int i = idx >> 6, k = idx & 63;
            As[i][k] = fw[(r0 + i) * 256 + k0 + k];
            int n = n0 + i;
            Bs[k][i] = (n < O_) ? lw[(size_t)n * 256 + k0 + k] : 0.f;
        }
        __syncthreads();
#pragma unroll
        for (int k = 0; k < 64; k++) {
            float a[4], bb[4];
#pragma unroll
            for (int i = 0; i < 4; i++) a[i] = As[ty * 4 + i][k];
#pragma unroll
            for (int j = 0; j < 4; j++) bb[j] = Bs[k][tx * 4 + j];
#pragma unroll
            for (int i = 0; i < 4; i++)
#pragma unroll
                for (int j = 0; j < 4; j++) acc[i][j] += a[i] * bb[j];
        }
    }
#pragma unroll
    for (int i = 0; i < 4; i++)
#pragma unroll
        for (int j = 0; j < 4; j++) {
            int n = n0 + tx * 4 + j;
            if (n < O_) out[(size_t)(r0 + ty * 4 + i) * O_ + n] = acc[i][j] + lb[n];
        }
}

extern "C" void kernel_launch(void* const* d_in, const int* in_sizes, int n_in,
                              void* d_out, int out_size, void* d_ws, size_t ws_size,
                              hipStream_t stream) {
    const int* tok = (const int*)d_in[0];
    const float* emb = (const float*)d_in[1];
    const float* Wb = (const float*)d_in[2];
    const float* lw = (const float*)d_in[3];
    const float* lb = (const float*)d_in[4];
    float* out = (float*)d_out;

    char* ws = (char*)d_ws;
    unsigned short* E   = (unsigned short*)(ws);                // 67,108,864 B
    unsigned short* Wbf = (unsigned short*)(ws + 67108864);     //    131,072 B
    float*          fwp = (float*)(ws + 67239936);              //    524,288 B

    hipLaunchKernelGGL(k_gather, dim3(16384), dim3(256), 0, stream, tok, emb, E);
    hipLaunchKernelGGL(k_wt,     dim3(256),   dim3(256), 0, stream, Wb, Wbf);
    hipLaunchKernelGGL(k_attn,   dim3(512),   dim3(1024), 0, stream, E, Wbf, fwp);
    hipLaunchKernelGGL(k_out,    dim3(16, 8), dim3(256), 0, stream, fwp, lw, lb, out);
}

// Round 4
// 127.573 us; speedup vs baseline: 1.4101x; 1.4101x over previous
//
#include <hip/hip_runtime.h>
#include <hip/hip_bf16.h>
#include <math.h>

// Problem constants
#define B_ 512
#define L_ 256
#define D_ 256
#define V_ 100000
#define O_ 1000

typedef __attribute__((ext_vector_type(8))) short short8;
typedef __attribute__((ext_vector_type(4))) float f32x4;

static __device__ __forceinline__ unsigned short f2bf(float f) {
    union { float f; unsigned u; } v; v.f = f;
    unsigned r = v.u + 0x7FFFu + ((v.u >> 16) & 1u);   // RNE (inputs are finite)
    return (unsigned short)(r >> 16);
}
static __device__ __forceinline__ float bf2f(unsigned short u) {
    union { unsigned u; float f; } v; v.u = ((unsigned)u) << 16;
    return v.f;
}

// ---------------- Kernel 1: embedding gather + cast to bf16 ----------------
__global__ __launch_bounds__(256) void k_gather(const int* __restrict__ tok,
                                                const float* __restrict__ emb,
                                                unsigned short* __restrict__ E) {
    int gid = blockIdx.x * 256 + threadIdx.x;     // 4,194,304 threads
    int row = gid >> 5;                            // 32 threads per 256-elem row
    int off = (gid & 31) << 3;
    int t = tok[row];
    const float4* src = (const float4*)(emb + (size_t)t * D_ + off);
    float4 a = src[0], b = src[1];
    short8 o;
    o[0] = (short)f2bf(a.x); o[1] = (short)f2bf(a.y);
    o[2] = (short)f2bf(a.z); o[3] = (short)f2bf(a.w);
    o[4] = (short)f2bf(b.x); o[5] = (short)f2bf(b.y);
    o[6] = (short)f2bf(b.z); o[7] = (short)f2bf(b.w);
    *(short8*)(E + (size_t)row * D_ + off) = o;
}

// ---------------- Kernel 1b: W_b cast to bf16 (row-major) ----------------
__global__ __launch_bounds__(256) void k_wt(const float* __restrict__ Wb,
                                            unsigned short* __restrict__ Wbf) {
    int i = blockIdx.x * 256 + threadIdx.x;       // 65536
    Wbf[i] = f2bf(Wb[i]);
}

// ---------------- Kernel 2 (fused): per-batch G = E_b * W_b * E_b^T ----------------
// One block per batch, 512 threads (8 waves), 1 block/CU (160KB LDS exactly).
// - E_b fully staged in LDS (128KB), XOR-swizzled: row r, 16B-chunk c at byte
//   r*512 + (c*16 ^ ((r&7)<<4)).   (conflict-free ds_read_b128 column-slices)
// - Each wave preloads its 64 Wb rows as MFMA A-frags into 128 VGPRs (read once).
// - m-loop (4 x 64 cols of G):
//     phase 1: Ht[m][d] = sum_e Wb[d,e]*E_b[m,e]  (i.e. H' transposed) -> 32KB LDS tile
//     phase 2: G[l][m] = sum_d E_b[l,d]*Ht[m,d]; per-lane running rowmax
// - tanh (monotone) -> softmax over L -> f_w = a^T E_b (from LDS).
__global__ __launch_bounds__(512, 2) void k_attn(const unsigned short* __restrict__ E,
                                                 const unsigned short* __restrict__ Wbf,
                                                 float* __restrict__ fw) {
    __shared__ char lds[163840];
    char* EsC = lds;                                   // 128KB: swizzled E_b
    char* HtC = lds + 131072;                          // 32KB: Httile (64 rows x 512B, swizzled)
    float* red2    = (float*)(lds + 131072);           // overlay: 2 x 256 f32
    float* scratch = (float*)(lds + 131072 + 2048);    // overlay: 16 f32
    float* fred    = (float*)(lds + 131072 + 2112);    // overlay: 16 x 256 f32

    int b = blockIdx.x;
    int tid = threadIdx.x;
    int wid = tid >> 6, ln = tid & 63;
    int l16 = ln & 15, gp = ln >> 4;
    const unsigned short* Eb = E + ((size_t)b << 16);

    int i0 = (wid >> 1) * 64;   // this wave's Wb row block (phase 1) / G row block (phase 2)
    int jh = (wid & 1) * 32;    // this wave's j-half (phase 1) / m-half (phase 2)

    // ---- Wb A-fragment register preload: rows [i0, i0+64), all K (32 short8 = 128 VGPR) ----
    short8 wfr[8][4];
#pragma unroll
    for (int k = 0; k < 8; k++)
#pragma unroll
        for (int rf = 0; rf < 4; rf++)
            wfr[k][rf] = *(const short8*)(Wbf + ((i0 + rf * 16 + l16) << 8) + k * 32 + gp * 8);

    // ---- stage E_b into LDS, swizzled (128KB, coalesced global reads) ----
#pragma unroll
    for (int it = 0; it < 16; it++) {
        int c = it * 512 + tid;          // 8192 chunks of 16B
        int row = c >> 5, c16 = c & 31;
        short8 v = *(const short8*)(Eb + (row << 8) + (c16 << 3));
        int byt = (row << 9) | ((c16 << 4) ^ ((row & 7) << 4));
        *(short8*)(EsC + byt) = v;
    }
    __syncthreads();

    float rmax[16];
#pragma unroll
    for (int i = 0; i < 16; i++) rmax[i] = -1e30f;

    for (int mt = 0; mt < 4; mt++) {
        int m0 = mt * 64;
        // ---- phase 1: Ht rows [m0..m0+64) ----
        {
            f32x4 acc[4][2] = {};
            for (int k0 = 0; k0 < 256; k0 += 32) {
                int kk2 = (k0 + gp * 8) * 2;            // byte col in a 512B row
                short8 bfr[2];
#pragma unroll
                for (int cf = 0; cf < 2; cf++) {
                    int j = m0 + jh + cf * 16 + l16;
                    int byt = (j << 9) | (kk2 ^ ((j & 7) << 4));
                    bfr[cf] = *(const short8*)(EsC + byt);
                }
                int ks = k0 >> 5;
#pragma unroll
                for (int rf = 0; rf < 4; rf++)
#pragma unroll
                    for (int cf = 0; cf < 2; cf++)
                        acc[rf][cf] = __builtin_amdgcn_mfma_f32_16x16x32_bf16(
                            wfr[ks][rf], bfr[cf], acc[rf][cf], 0, 0, 0);
            }
            // store transposed (H'[i][j] -> Ht[j-m0][i]), 8B packs, swizzled
#pragma unroll
            for (int rf = 0; rf < 4; rf++)
#pragma unroll
                for (int cf = 0; cf < 2; cf++) {
                    int i = i0 + rf * 16 + gp * 4;      // 4 consecutive i
                    int jl = jh + cf * 16 + l16;        // local Ht row
                    unsigned long long pk;
                    unsigned short* p = (unsigned short*)&pk;
                    p[0] = f2bf(acc[rf][cf][0]);
                    p[1] = f2bf(acc[rf][cf][1]);
                    p[2] = f2bf(acc[rf][cf][2]);
                    p[3] = f2bf(acc[rf][cf][3]);
                    int byt = (jl << 9) | ((i * 2) ^ ((jl & 7) << 4));
                    *(unsigned long long*)(HtC + byt) = pk;
                }
        }
        __syncthreads();
        // ---- phase 2: G[l][m0..m0+64) with running rowmax ----
        {
            f32x4 acc[4][2] = {};
            for (int k0 = 0; k0 < 256; k0 += 32) {
                int kk2 = (k0 + gp * 8) * 2;
                short8 a[4];
#pragma unroll
                for (int rf = 0; rf < 4; rf++) {
                    int l = i0 + rf * 16 + l16;
                    int byt = (l << 9) | (kk2 ^ ((l & 7) << 4));
                    a[rf] = *(const short8*)(EsC + byt);
                }
                short8 bb[2];
#pragma unroll
                for (int cf = 0; cf < 2; cf++) {
                    int m = jh + cf * 16 + l16;         // local Ht row
                    int byt = (m << 9) | (kk2 ^ ((m & 7) << 4));
                    bb[cf] = *(const short8*)(HtC + byt);
                }
#pragma unroll
                for (int rf = 0; rf < 4; rf++)
#pragma unroll
                    for (int cf = 0; cf < 2; cf++)
                        acc[rf][cf] = __builtin_amdgcn_mfma_f32_16x16x32_bf16(
                            a[rf], bb[cf], acc[rf][cf], 0, 0, 0);
            }
#pragma unroll
            for (int rf = 0; rf < 4; rf++)
#pragma unroll
                for (int r = 0; r < 4; r++)
                    rmax[rf * 4 + r] = fmaxf(rmax[rf * 4 + r],
                                             fmaxf(acc[rf][0][r], acc[rf][1][r]));
        }
        __syncthreads();   // protects Httile for next phase-1 / red2 overlay after last iter
    }

    // ---- reduce rowmax across l16 lanes, publish to red2 (two m-halves per l-block) ----
#pragma unroll
    for (int i = 0; i < 16; i++) {
        float v = rmax[i];
        v = fmaxf(v, __shfl_xor(v, 1));
        v = fmaxf(v, __shfl_xor(v, 2));
        v = fmaxf(v, __shfl_xor(v, 4));
        v = fmaxf(v, __shfl_xor(v, 8));
        rmax[i] = v;
    }
    if (l16 == 0) {
#pragma unroll
        for (int rf = 0; rf < 4; rf++)
#pragma unroll
            for (int r = 0; r < 4; r++)
                red2[(wid & 1) * 256 + i0 + rf * 16 + gp * 4 + r] = rmax[rf * 4 + r];
    }
    __syncthreads();

    // ---- tanh + softmax over the 256 row-maxima ----
    float x = -1e30f;
    if (tid < 256) x = tanhf(fmaxf(red2[tid], red2[256 + tid]));
    float mx = x;
#pragma unroll
    for (int s = 1; s < 64; s <<= 1) mx = fmaxf(mx, __shfl_xor(mx, s));
    if (ln == 0) scratch[wid] = mx;
    __syncthreads();
    float bm = scratch[0];
#pragma unroll
    for (int i = 1; i < 8; i++) bm = fmaxf(bm, scratch[i]);
    float e = (tid < 256) ? expf(x - bm) : 0.f;
    float sm = e;
#pragma unroll
    for (int s = 1; s < 64; s <<= 1) sm += __shfl_xor(sm, s);
    if (ln == 0) scratch[8 + wid] = sm;
    __syncthreads();
    float tot = 0.f;
#pragma unroll
    for (int i = 0; i < 8; i++) tot += scratch[8 + i];
    if (tid < 256) red2[tid] = e / tot;    // aq (thread t only touches its own slot)
    __syncthreads();

    // ---- f_w[d] = sum_l aq[l] * E_b[l][d]  (E from LDS, partials in fred) ----
    {
        int g = tid >> 5;                    // 0..15 -> l-range [16g, 16g+16)
        int d0 = (tid & 31) << 3;            // 8 d's per thread
        float s0[8] = {0.f, 0.f, 0.f, 0.f, 0.f, 0.f, 0.f, 0.f};
        int lbase = g << 4;
#pragma unroll
        for (int li = 0; li < 16; li++) {
            int l = lbase + li;
            float aql = red2[l];
            int byt = (l << 9) | ((d0 * 2) ^ ((l & 7) << 4));
            short8 v = *(const short8*)(EsC + byt);
#pragma unroll
            for (int jj = 0; jj < 8; jj++)
                s0[jj] += aql * bf2f((unsigned short)v[jj]);
        }
        f32x4 w0, w1;
        w0[0] = s0[0]; w0[1] = s0[1]; w0[2] = s0[2]; w0[3] = s0[3];
        w1[0] = s0[4]; w1[1] = s0[5]; w1[2] = s0[6]; w1[3] = s0[7];
        *(f32x4*)(fred + g * 256 + d0) = w0;
        *(f32x4*)(fred + g * 256 + d0 + 4) = w1;
    }
    __syncthreads();
    if (tid < 256) {
        float f = 0.f;
#pragma unroll
        for (int g2 = 0; g2 < 16; g2++) f += fred[g2 * 256 + tid];
        fw[(b << 8) + tid] = f;
    }
}

// ---------------- Kernel 3: out = f_w @ lin_w^T + lin_b  (fp32 tiled GEMM) ----------------
__global__ __launch_bounds__(256) void k_out(const float* __restrict__ fw,
                                             const float* __restrict__ lw,
                                             const float* __restrict__ lb,
                                             float* __restrict__ out) {
    __shared__ float As[64][65];
    __shared__ float Bs[64][65];
    int tx = threadIdx.x & 15, ty = threadIdx.x >> 4;
    int r0 = blockIdx.y * 64, n0 = blockIdx.x * 64;
    float acc[4][4] = {};
    for (int k0 = 0; k0 < 256; k0 += 64) {
        __syncthreads();
#pragma unroll
        for (int it = 0; it < 16; it++) {
            int idx = it * 256 + threadIdx.x;
            int i = idx >> 6, k = idx & 63;
            As[i][k] = fw[(r0 + i) * 256 + k0 + k];
            int n = n0 + i;
            Bs[k][i] = (n < O_) ? lw[(size_t)n * 256 + k0 + k] : 0.f;
        }
        __syncthreads();
#pragma unroll
        for (int k = 0; k < 64; k++) {
            float a[4], bb[4];
#pragma unroll
            for (int i = 0; i < 4; i++) a[i] = As[ty * 4 + i][k];
#pragma unroll
            for (int j = 0; j < 4; j++) bb[j] = Bs[k][tx * 4 + j];
#pragma unroll
            for (int i = 0; i < 4; i++)
#pragma unroll
                for (int j = 0; j < 4; j++) acc[i][j] += a[i] * bb[j];
        }
    }
#pragma unroll
    for (int i = 0; i < 4; i++)
#pragma unroll
        for (int j = 0; j < 4; j++) {
            int n = n0 + tx * 4 + j;
            if (n < O_) out[(size_t)(r0 + ty * 4 + i) * O_ + n] = acc[i][j] + lb[n];
        }
}

extern "C" void kernel_launch(void* const* d_in, const int* in_sizes, int n_in,
                              void* d_out, int out_size, void* d_ws, size_t ws_size,
                              hipStream_t stream) {
    const int* tok = (const int*)d_in[0];
    const float* emb = (const float*)d_in[1];
    const float* Wb = (const float*)d_in[2];
    const float* lw = (const float*)d_in[3];
    const float* lb = (const float*)d_in[4];
    float* out = (float*)d_out;

    char* ws = (char*)d_ws;
    unsigned short* E   = (unsigned short*)(ws);                // 67,108,864 B
    unsigned short* Wbf = (unsigned short*)(ws + 67108864);     //    131,072 B
    float*          fwp = (float*)(ws + 67239936);              //    524,288 B

    hipLaunchKernelGGL(k_gather, dim3(16384), dim3(256), 0, stream, tok, emb, E);
    hipLaunchKernelGGL(k_wt,     dim3(256),   dim3(256), 0, stream, Wb, Wbf);
    hipLaunchKernelGGL(k_attn,   dim3(512),   dim3(512), 0, stream, E, Wbf, fwp);
    hipLaunchKernelGGL(k_out,    dim3(16, 8), dim3(256), 0, stream, fwp, lw, lb, out);
}

// Round 5
// 106.688 us; speedup vs baseline: 1.6861x; 1.1958x over previous
//
#include <hip/hip_runtime.h>
#include <hip/hip_bf16.h>
#include <math.h>

// Problem constants
#define B_ 512
#define L_ 256
#define D_ 256
#define V_ 100000
#define O_ 1000

typedef __attribute__((ext_vector_type(8))) short short8;
typedef __attribute__((ext_vector_type(4))) float f32x4;

static __device__ __forceinline__ unsigned short f2bf(float f) {
    union { float f; unsigned u; } v; v.f = f;
    unsigned r = v.u + 0x7FFFu + ((v.u >> 16) & 1u);   // RNE (inputs are finite)
    return (unsigned short)(r >> 16);
}
static __device__ __forceinline__ float bf2f(unsigned short u) {
    union { unsigned u; float f; } v; v.u = ((unsigned)u) << 16;
    return v.f;
}

// ---------------- Kernel 1: W_b cast to bf16 (row-major) ----------------
__global__ __launch_bounds__(256) void k_wt(const float* __restrict__ Wb,
                                            unsigned short* __restrict__ Wbf) {
    int i = blockIdx.x * 256 + threadIdx.x;       // 65536
    Wbf[i] = f2bf(Wb[i]);
}

// ---------------- Kernel 2 (fused): per-batch  gather + G = E_b*W_b*E_b^T + softmax + f_w ----
// One block per batch, 512 threads (8 waves), 1 block/CU (160KB LDS exactly).
// - E_b gathered DIRECTLY from the fp32 embedding table into LDS (bf16, XOR-swizzled:
//   row r, 16B-chunk c at byte r*512 + (c*16 ^ ((r&7)<<4))) — no global E intermediate.
// - Each wave preloads its 64 Wb rows as MFMA A-frags into 128 VGPRs (read once).
// - m-loop (4 x 64 cols of G):
//     phase 1: Ht[m][d] = sum_e Wb[d,e]*E_b[m,e]  (H' transposed) -> 32KB LDS tile
//     phase 2: G[l][m] = sum_d E_b[l,d]*Ht[m,d]; per-lane running rowmax
// - tanh (monotone: tanh(max)=max(tanh)) -> softmax over L -> f_w = a^T E_b (from LDS).
__global__ __launch_bounds__(512, 2) void k_attn(const int* __restrict__ tok,
                                                 const float* __restrict__ emb,
                                                 const unsigned short* __restrict__ Wbf,
                                                 float* __restrict__ fw) {
    __shared__ char lds[163840];
    char* EsC = lds;                                   // 128KB: swizzled E_b
    char* HtC = lds + 131072;                          // 32KB: Ht tile (64 rows x 512B, swizzled)
    float* red2    = (float*)(lds + 131072);           // overlay: 2 x 256 f32
    float* scratch = (float*)(lds + 131072 + 2048);    // overlay: 16 f32
    float* fred    = (float*)(lds + 131072 + 2112);    // overlay: 16 x 256 f32

    int b = blockIdx.x;
    int tid = threadIdx.x;
    int wid = tid >> 6, ln = tid & 63;
    int l16 = ln & 15, gp = ln >> 4;

    int i0 = (wid >> 1) * 64;   // this wave's Wb row block (phase 1) / G row block (phase 2)
    int jh = (wid & 1) * 32;    // this wave's j-half (phase 1) / m-half (phase 2)

    // ---- Wb A-fragment register preload: rows [i0, i0+64), all K (32 short8 = 128 VGPR) ----
    short8 wfr[8][4];
#pragma unroll
    for (int k = 0; k < 8; k++)
#pragma unroll
        for (int rf = 0; rf < 4; rf++)
            wfr[k][rf] = *(const short8*)(Wbf + ((i0 + rf * 16 + l16) << 8) + k * 32 + gp * 8);

    // ---- gather E_b rows from emb into LDS, bf16 + swizzle (256 rows x 1KB fp32 reads) ----
#pragma unroll
    for (int it = 0; it < 16; it++) {
        int c = it * 512 + tid;          // 8192 chunks of 8 elems
        int row = c >> 5, c16 = c & 31;
        int t = tok[(b << 8) + row];     // 32 lanes same addr -> broadcast
        const float4* src = (const float4*)(emb + ((size_t)t << 8) + (c16 << 3));
        float4 a = src[0], bv = src[1];
        short8 o;
        o[0] = (short)f2bf(a.x);  o[1] = (short)f2bf(a.y);
        o[2] = (short)f2bf(a.z);  o[3] = (short)f2bf(a.w);
        o[4] = (short)f2bf(bv.x); o[5] = (short)f2bf(bv.y);
        o[6] = (short)f2bf(bv.z); o[7] = (short)f2bf(bv.w);
        int byt = (row << 9) | ((c16 << 4) ^ ((row & 7) << 4));
        *(short8*)(EsC + byt) = o;
    }
    __syncthreads();

    float rmax[16];
#pragma unroll
    for (int i = 0; i < 16; i++) rmax[i] = -1e30f;

    for (int mt = 0; mt < 4; mt++) {
        int m0 = mt * 64;
        // ---- phase 1: Ht rows [m0..m0+64) ----
        {
            f32x4 acc[4][2] = {};
            for (int k0 = 0; k0 < 256; k0 += 32) {
                int kk2 = (k0 + gp * 8) * 2;            // byte col in a 512B row
                short8 bfr[2];
#pragma unroll
                for (int cf = 0; cf < 2; cf++) {
                    int j = m0 + jh + cf * 16 + l16;
                    int byt = (j << 9) | (kk2 ^ ((j & 7) << 4));
                    bfr[cf] = *(const short8*)(EsC + byt);
                }
                int ks = k0 >> 5;
#pragma unroll
                for (int rf = 0; rf < 4; rf++)
#pragma unroll
                    for (int cf = 0; cf < 2; cf++)
                        acc[rf][cf] = __builtin_amdgcn_mfma_f32_16x16x32_bf16(
                            wfr[ks][rf], bfr[cf], acc[rf][cf], 0, 0, 0);
            }
            // store transposed (H'[i][j] -> Ht[j-m0][i]), 8B packs, swizzled
#pragma unroll
            for (int rf = 0; rf < 4; rf++)
#pragma unroll
                for (int cf = 0; cf < 2; cf++) {
                    int i = i0 + rf * 16 + gp * 4;      // 4 consecutive i
                    int jl = jh + cf * 16 + l16;        // local Ht row
                    unsigned long long pk;
                    unsigned short* p = (unsigned short*)&pk;
                    p[0] = f2bf(acc[rf][cf][0]);
                    p[1] = f2bf(acc[rf][cf][1]);
                    p[2] = f2bf(acc[rf][cf][2]);
                    p[3] = f2bf(acc[rf][cf][3]);
                    int byt = (jl << 9) | ((i * 2) ^ ((jl & 7) << 4));
                    *(unsigned long long*)(HtC + byt) = pk;
                }
        }
        __syncthreads();
        // ---- phase 2: G[l][m0..m0+64) with running rowmax ----
        {
            f32x4 acc[4][2] = {};
            for (int k0 = 0; k0 < 256; k0 += 32) {
                int kk2 = (k0 + gp * 8) * 2;
                short8 a[4];
#pragma unroll
                for (int rf = 0; rf < 4; rf++) {
                    int l = i0 + rf * 16 + l16;
                    int byt = (l << 9) | (kk2 ^ ((l & 7) << 4));
                    a[rf] = *(const short8*)(EsC + byt);
                }
                short8 bb[2];
#pragma unroll
                for (int cf = 0; cf < 2; cf++) {
                    int m = jh + cf * 16 + l16;         // local Ht row
                    int byt = (m << 9) | (kk2 ^ ((m & 7) << 4));
                    bb[cf] = *(const short8*)(HtC + byt);
                }
#pragma unroll
                for (int rf = 0; rf < 4; rf++)
#pragma unroll
                    for (int cf = 0; cf < 2; cf++)
                        acc[rf][cf] = __builtin_amdgcn_mfma_f32_16x16x32_bf16(
                            a[rf], bb[cf], acc[rf][cf], 0, 0, 0);
            }
#pragma unroll
            for (int rf = 0; rf < 4; rf++)
#pragma unroll
                for (int r = 0; r < 4; r++)
                    rmax[rf * 4 + r] = fmaxf(rmax[rf * 4 + r],
                                             fmaxf(acc[rf][0][r], acc[rf][1][r]));
        }
        __syncthreads();   // protects Ht tile for next phase-1 / red2 overlay after last iter
    }

    // ---- reduce rowmax across l16 lanes, publish to red2 (two m-halves per l-block) ----
#pragma unroll
    for (int i = 0; i < 16; i++) {
        float v = rmax[i];
        v = fmaxf(v, __shfl_xor(v, 1));
        v = fmaxf(v, __shfl_xor(v, 2));
        v = fmaxf(v, __shfl_xor(v, 4));
        v = fmaxf(v, __shfl_xor(v, 8));
        rmax[i] = v;
    }
    if (l16 == 0) {
#pragma unroll
        for (int rf = 0; rf < 4; rf++)
#pragma unroll
            for (int r = 0; r < 4; r++)
                red2[(wid & 1) * 256 + i0 + rf * 16 + gp * 4 + r] = rmax[rf * 4 + r];
    }
    __syncthreads();

    // ---- tanh + softmax over the 256 row-maxima ----
    float x = -1e30f;
    if (tid < 256) x = tanhf(fmaxf(red2[tid], red2[256 + tid]));
    float mx = x;
#pragma unroll
    for (int s = 1; s < 64; s <<= 1) mx = fmaxf(mx, __shfl_xor(mx, s));
    if (ln == 0) scratch[wid] = mx;
    __syncthreads();
    float bm = scratch[0];
#pragma unroll
    for (int i = 1; i < 8; i++) bm = fmaxf(bm, scratch[i]);
    float e = (tid < 256) ? expf(x - bm) : 0.f;
    float sm = e;
#pragma unroll
    for (int s = 1; s < 64; s <<= 1) sm += __shfl_xor(sm, s);
    if (ln == 0) scratch[8 + wid] = sm;
    __syncthreads();
    float tot = 0.f;
#pragma unroll
    for (int i = 0; i < 8; i++) tot += scratch[8 + i];
    if (tid < 256) red2[tid] = e / tot;    // aq (thread t only touches its own slot)
    __syncthreads();

    // ---- f_w[d] = sum_l aq[l] * E_b[l][d]  (E from LDS, partials in fred) ----
    {
        int g = tid >> 5;                    // 0..15 -> l-range [16g, 16g+16)
        int d0 = (tid & 31) << 3;            // 8 d's per thread
        float s0[8] = {0.f, 0.f, 0.f, 0.f, 0.f, 0.f, 0.f, 0.f};
        int lbase = g << 4;
#pragma unroll
        for (int li = 0; li < 16; li++) {
            int l = lbase + li;
            float aql = red2[l];
            int byt = (l << 9) | ((d0 * 2) ^ ((l & 7) << 4));
            short8 v = *(const short8*)(EsC + byt);
#pragma unroll
            for (int jj = 0; jj < 8; jj++)
                s0[jj] += aql * bf2f((unsigned short)v[jj]);
        }
        f32x4 w0, w1;
        w0[0] = s0[0]; w0[1] = s0[1]; w0[2] = s0[2]; w0[3] = s0[3];
        w1[0] = s0[4]; w1[1] = s0[5]; w1[2] = s0[6]; w1[3] = s0[7];
        *(f32x4*)(fred + g * 256 + d0) = w0;
        *(f32x4*)(fred + g * 256 + d0 + 4) = w1;
    }
    __syncthreads();
    if (tid < 256) {
        float f = 0.f;
#pragma unroll
        for (int g2 = 0; g2 < 16; g2++) f += fred[g2 * 256 + tid];
        fw[(b << 8) + tid] = f;
    }
}

// ---------------- Kernel 3: out = f_w @ lin_w^T + lin_b  (fp32 tiled GEMM) ----------------
__global__ __launch_bounds__(256) void k_out(const float* __restrict__ fw,
                                             const float* __restrict__ lw,
                                             const float* __restrict__ lb,
                                             float* __restrict__ out) {
    __shared__ float As[64][65];
    __shared__ float Bs[64][65];
    int tx = threadIdx.x & 15, ty = threadIdx.x >> 4;
    int r0 = blockIdx.y * 64, n0 = blockIdx.x * 64;
    float acc[4][4] = {};
    for (int k0 = 0; k0 < 256; k0 += 64) {
        __syncthreads();
#pragma unroll
        for (int it = 0; it < 16; it++) {
            int idx = it * 256 + threadIdx.x;
            int i = idx >> 6, k = idx & 63;
            As[i][k] = fw[(r0 + i) * 256 + k0 + k];
            int n = n0 + i;
            Bs[k][i] = (n < O_) ? lw[(size_t)n * 256 + k0 + k] : 0.f;
        }
        __syncthreads();
#pragma unroll
        for (int k = 0; k < 64; k++) {
            float a[4], bb[4];
#pragma unroll
            for (int i = 0; i < 4; i++) a[i] = As[ty * 4 + i][k];
#pragma unroll
            for (int j = 0; j < 4; j++) bb[j] = Bs[k][tx * 4 + j];
#pragma unroll
            for (int i = 0; i < 4; i++)
#pragma unroll
                for (int j = 0; j < 4; j++) acc[i][j] += a[i] * bb[j];
        }
    }
#pragma unroll
    for (int i = 0; i < 4; i++)
#pragma unroll
        for (int j = 0; j < 4; j++) {
            int n = n0 + tx * 4 + j;
            if (n < O_) out[(size_t)(r0 + ty * 4 + i) * O_ + n] = acc[i][j] + lb[n];
        }
}

extern "C" void kernel_launch(void* const* d_in, const int* in_sizes, int n_in,
                              void* d_out, int out_size, void* d_ws, size_t ws_size,
                              hipStream_t stream) {
    const int* tok = (const int*)d_in[0];
    const float* emb = (const float*)d_in[1];
    const float* Wb = (const float*)d_in[2];
    const float* lw = (const float*)d_in[3];
    const float* lb = (const float*)d_in[4];
    float* out = (float*)d_out;

    char* ws = (char*)d_ws;
    unsigned short* Wbf = (unsigned short*)(ws);            // 131,072 B
    float*          fwp = (float*)(ws + 131072);            // 524,288 B

    hipLaunchKernelGGL(k_wt,   dim3(256),   dim3(256), 0, stream, Wb, Wbf);
    hipLaunchKernelGGL(k_attn, dim3(512),   dim3(512), 0, stream, tok, emb, Wbf, fwp);
    hipLaunchKernelGGL(k_out,  dim3(16, 8), dim3(256), 0, stream, fwp, lw, lb, out);
}

// Round 6
// 79.870 us; speedup vs baseline: 2.2523x; 1.3358x over previous
//
#include <hip/hip_runtime.h>
#include <hip/hip_bf16.h>
#include <math.h>

// Problem constants
#define B_ 512
#define L_ 256
#define D_ 256
#define V_ 100000
#define O_ 1000

typedef __attribute__((ext_vector_type(8))) short short8;
typedef __attribute__((ext_vector_type(4))) float f32x4;

static __device__ __forceinline__ unsigned short f2bf(float f) {
    union { float f; unsigned u; } v; v.f = f;
    unsigned r = v.u + 0x7FFFu + ((v.u >> 16) & 1u);   // RNE (inputs are finite)
    return (unsigned short)(r >> 16);
}
static __device__ __forceinline__ float bf2f(unsigned short u) {
    union { unsigned u; float f; } v; v.u = ((unsigned)u) << 16;
    return v.f;
}

// ---------------- Kernel 1: W_b cast to bf16 (row-major) ----------------
__global__ __launch_bounds__(256) void k_wt(const float* __restrict__ Wb,
                                            unsigned short* __restrict__ Wbf) {
    int i = blockIdx.x * 256 + threadIdx.x;       // 65536
    Wbf[i] = f2bf(Wb[i]);
}

// ---------------- Kernel 2 (fused): per-batch  gather + G = E_b*W_b*E_b^T + softmax + f_w ----
// One block per batch, 512 threads (8 waves), 1 block/CU (160KB LDS).
// - Gather: wave-per-row (row wave-uniform -> tok broadcast load; 64 lanes read the
//   full 1KB fp32 row coalesced), bf16-cast into XOR-swizzled LDS
//   (row r, byte col c at r*512 + (c ^ ((r&7)<<4))).
// - Register-resident operands: each wave holds 32 Wb rows (wfr, 64 VGPR) and its
//   32 E rows (efr, 64 VGPR) as MFMA A-frags for the whole kernel.
// - m-loop (4 x 64 cols of G):
//     phase 1: Ht[m][d] = sum_e Wb[d,e]*E_b[m,e]  (H' transposed) -> 32KB LDS tile
//              (wave tile 32 Wb-rows x 64 cols; A from wfr regs, B = 4 ds_read_b128)
//     phase 2: G[l][m] = sum_d E_b[l,d]*Ht[m,d]; per-lane running rowmax
//              (wave tile 32 G-rows x 64 cols; A from efr regs, B = 4 ds_read_b128)
// - tanh (monotone: tanh(max)=max(tanh)) -> softmax over L -> f_w = a^T E_b (from LDS).
__global__ __launch_bounds__(512, 2) void k_attn(const int* __restrict__ tok,
                                                 const float* __restrict__ emb,
                                                 const unsigned short* __restrict__ Wbf,
                                                 float* __restrict__ fw) {
    __shared__ char lds[163840];
    char* EsC = lds;                                   // 128KB: swizzled E_b
    char* HtC = lds + 131072;                          // 32KB: Ht tile (64 rows x 512B, swizzled)
    float* red2    = (float*)(lds + 131072);           // overlay: 256 f32
    float* scratch = (float*)(lds + 131072 + 1024);    // overlay: 16 f32
    float* fred    = (float*)(lds + 131072 + 1152);    // overlay: 16 x 256 f32

    int b = blockIdx.x;
    int tid = threadIdx.x;
    int wid = tid >> 6, ln = tid & 63;
    int l16 = ln & 15, gp = ln >> 4;

    // ---- gather: wave per row, 32 rows per wave; full 1KB row per wave-instr ----
    {
        const int* tb = tok + (b << 8);
#pragma unroll
        for (int it = 0; it < 32; it++) {
            int row = it * 8 + wid;
            int t = tb[row];                                  // wave-uniform -> broadcast
            float4 v = *(const float4*)(emb + ((size_t)t << 8) + (ln << 2));
            unsigned long long pk;
            unsigned short* p = (unsigned short*)&pk;
            p[0] = f2bf(v.x); p[1] = f2bf(v.y); p[2] = f2bf(v.z); p[3] = f2bf(v.w);
            int byt = (row << 9) | ((ln << 3) ^ ((row & 7) << 4));
            *(unsigned long long*)(EsC + byt) = pk;
        }
    }

    // ---- Wb A-frag preload (global, L2-hot): rows [i0, i0+32) -> 64 VGPR ----
    int i0 = wid * 32;
    short8 wfr[8][2];
#pragma unroll
    for (int k = 0; k < 8; k++)
#pragma unroll
        for (int rf = 0; rf < 2; rf++)
            wfr[k][rf] = *(const short8*)(Wbf + ((i0 + rf * 16 + l16) << 8) + k * 32 + gp * 8);
    __syncthreads();

    // ---- E A-frag preload (from LDS): rows [l0, l0+32) -> 64 VGPR ----
    int l0 = i0;
    short8 efr[8][2];
#pragma unroll
    for (int k = 0; k < 8; k++)
#pragma unroll
        for (int rf = 0; rf < 2; rf++) {
            int l = l0 + rf * 16 + l16;
            int byt = (l << 9) | ((k * 64 + gp * 16) ^ ((l & 7) << 4));
            efr[k][rf] = *(const short8*)(EsC + byt);
        }

    float rmax[8];
#pragma unroll
    for (int i = 0; i < 8; i++) rmax[i] = -1e30f;

    for (int mt = 0; mt < 4; mt++) {
        int m0 = mt * 64;
        // ---- phase 1: Ht rows [m0..m0+64), this wave contributes cols [i0, i0+32) ----
        {
            f32x4 acc[2][4] = {};
#pragma unroll
            for (int k0 = 0; k0 < 256; k0 += 32) {
                int kk2 = (k0 + gp * 8) * 2;            // byte col in a 512B row
                short8 bfr[4];
#pragma unroll
                for (int cf = 0; cf < 4; cf++) {
                    int jg = m0 + cf * 16 + l16;
                    int byt = (jg << 9) | (kk2 ^ ((jg & 7) << 4));
                    bfr[cf] = *(const short8*)(EsC + byt);
                }
                int ks = k0 >> 5;
#pragma unroll
                for (int rf = 0; rf < 2; rf++)
#pragma unroll
                    for (int cf = 0; cf < 4; cf++)
                        acc[rf][cf] = __builtin_amdgcn_mfma_f32_16x16x32_bf16(
                            wfr[ks][rf], bfr[cf], acc[rf][cf], 0, 0, 0);
            }
            // store transposed (H'[i][j] -> Ht[j-m0][i]), 8B packs, swizzled
#pragma unroll
            for (int rf = 0; rf < 2; rf++)
#pragma unroll
                for (int cf = 0; cf < 4; cf++) {
                    int i = i0 + rf * 16 + gp * 4;      // 4 consecutive i
                    int jl = cf * 16 + l16;             // local Ht row
                    unsigned long long pk;
                    unsigned short* p = (unsigned short*)&pk;
                    p[0] = f2bf(acc[rf][cf][0]);
                    p[1] = f2bf(acc[rf][cf][1]);
                    p[2] = f2bf(acc[rf][cf][2]);
                    p[3] = f2bf(acc[rf][cf][3]);
                    int byt = (jl << 9) | ((i * 2) ^ ((jl & 7) << 4));
                    *(unsigned long long*)(HtC + byt) = pk;
                }
        }
        __syncthreads();
        // ---- phase 2: G rows [l0..l0+32) x cols [m0..m0+64), running rowmax ----
        {
            f32x4 acc[2][4] = {};
#pragma unroll
            for (int k0 = 0; k0 < 256; k0 += 32) {
                int kk2 = (k0 + gp * 8) * 2;
                short8 bb[4];
#pragma unroll
                for (int cf = 0; cf < 4; cf++) {
                    int m = cf * 16 + l16;              // local Ht row
                    int byt = (m << 9) | (kk2 ^ ((m & 7) << 4));
                    bb[cf] = *(const short8*)(HtC + byt);
                }
                int ks = k0 >> 5;
#pragma unroll
                for (int rf = 0; rf < 2; rf++)
#pragma unroll
                    for (int cf = 0; cf < 4; cf++)
                        acc[rf][cf] = __builtin_amdgcn_mfma_f32_16x16x32_bf16(
                            efr[ks][rf], bb[cf], acc[rf][cf], 0, 0, 0);
            }
#pragma unroll
            for (int rf = 0; rf < 2; rf++)
#pragma unroll
                for (int r = 0; r < 4; r++) {
                    float mx = fmaxf(fmaxf(acc[rf][0][r], acc[rf][1][r]),
                                     fmaxf(acc[rf][2][r], acc[rf][3][r]));
                    rmax[rf * 4 + r] = fmaxf(rmax[rf * 4 + r], mx);
                }
        }
        __syncthreads();   // protects Ht tile for next phase-1 / overlays after last iter
    }

    // ---- reduce rowmax across l16 lanes, publish to red2 ----
#pragma unroll
    for (int i = 0; i < 8; i++) {
        float v = rmax[i];
        v = fmaxf(v, __shfl_xor(v, 1));
        v = fmaxf(v, __shfl_xor(v, 2));
        v = fmaxf(v, __shfl_xor(v, 4));
        v = fmaxf(v, __shfl_xor(v, 8));
        rmax[i] = v;
    }
    if (l16 == 0) {
#pragma unroll
        for (int rf = 0; rf < 2; rf++)
#pragma unroll
            for (int r = 0; r < 4; r++)
                red2[l0 + rf * 16 + gp * 4 + r] = rmax[rf * 4 + r];
    }
    __syncthreads();

    // ---- tanh + softmax over the 256 row-maxima ----
    float x = -1e30f;
    if (tid < 256) x = tanhf(red2[tid]);
    float mx = x;
#pragma unroll
    for (int s = 1; s < 64; s <<= 1) mx = fmaxf(mx, __shfl_xor(mx, s));
    if (ln == 0) scratch[wid] = mx;
    __syncthreads();
    float bm = scratch[0];
#pragma unroll
    for (int i = 1; i < 8; i++) bm = fmaxf(bm, scratch[i]);
    float e = (tid < 256) ? expf(x - bm) : 0.f;
    float sm = e;
#pragma unroll
    for (int s = 1; s < 64; s <<= 1) sm += __shfl_xor(sm, s);
    if (ln == 0) scratch[8 + wid] = sm;
    __syncthreads();
    float tot = 0.f;
#pragma unroll
    for (int i = 0; i < 8; i++) tot += scratch[8 + i];
    if (tid < 256) red2[tid] = e / tot;    // aq (thread t only touches its own slot)
    __syncthreads();

    // ---- f_w[d] = sum_l aq[l] * E_b[l][d]  (E from LDS, partials in fred) ----
    {
        int g = tid >> 5;                    // 0..15 -> l-range [16g, 16g+16)
        int d0 = (tid & 31) << 3;            // 8 d's per thread
        float s0[8] = {0.f, 0.f, 0.f, 0.f, 0.f, 0.f, 0.f, 0.f};
        int lbase = g << 4;
#pragma unroll
        for (int li = 0; li < 16; li++) {
            int l = lbase + li;
            float aql = red2[l];
            int byt = (l << 9) | ((d0 * 2) ^ ((l & 7) << 4));
            short8 v = *(const short8*)(EsC + byt);
#pragma unroll
            for (int jj = 0; jj < 8; jj++)
                s0[jj] += aql * bf2f((unsigned short)v[jj]);
        }
        f32x4 w0, w1;
        w0[0] = s0[0]; w0[1] = s0[1]; w0[2] = s0[2]; w0[3] = s0[3];
        w1[0] = s0[4]; w1[1] = s0[5]; w1[2] = s0[6]; w1[3] = s0[7];
        *(f32x4*)(fred + g * 256 + d0) = w0;
        *(f32x4*)(fred + g * 256 + d0 + 4) = w1;
    }
    __syncthreads();
    if (tid < 256) {
        float f = 0.f;
#pragma unroll
        for (int g2 = 0; g2 < 16; g2++) f += fred[g2 * 256 + tid];
        fw[(b << 8) + tid] = f;
    }
}

// ---------------- Kernel 3: out = f_w @ lin_w^T + lin_b  (fp32 tiled GEMM) ----------------
// Tile 32(M)x64(N), 256 blocks (full CU coverage), float4 staging.
__global__ __launch_bounds__(256) void k_out(const float* __restrict__ fw,
                                             const float* __restrict__ lw,
                                             const float* __restrict__ lb,
                                             float* __restrict__ out) {
    __shared__ float As[32][68];
    __shared__ float Bs[64][65];
    int tid = threadIdx.x;
    int tx = tid & 15, ty = tid >> 4;
    int r0 = blockIdx.y * 32, n0 = blockIdx.x * 64;
    float acc[2][4] = {};
    for (int k0 = 0; k0 < 256; k0 += 64) {
        __syncthreads();
#pragma unroll
        for (int it = 0; it < 2; it++) {
            int idx = it * 256 + tid;          // 512 float4 for As
            int i = idx >> 4, k4 = (idx & 15) << 2;
            *(float4*)&As[i][k4] = *(const float4*)&fw[(r0 + i) * 256 + k0 + k4];
        }
#pragma unroll
        for (int it = 0; it < 4; it++) {
            int idx = it * 256 + tid;          // 1024 float4 for Bs (transposed store)
            int n = idx >> 4, k4 = (idx & 15) << 2;
            int nn = n0 + n;
            float4 v = {0.f, 0.f, 0.f, 0.f};
            if (nn < O_) v = *(const float4*)&lw[(size_t)nn * 256 + k0 + k4];
            Bs[k4][n] = v.x; Bs[k4 + 1][n] = v.y; Bs[k4 + 2][n] = v.z; Bs[k4 + 3][n] = v.w;
        }
        __syncthreads();
#pragma unroll
        for (int k = 0; k < 64; k++) {
            float a0 = As[ty * 2][k], a1 = As[ty * 2 + 1][k];
            float b0 = Bs[k][tx * 4], b1 = Bs[k][tx * 4 + 1];
            float b2 = Bs[k][tx * 4 + 2], b3 = Bs[k][tx * 4 + 3];
            acc[0][0] += a0 * b0; acc[0][1] += a0 * b1; acc[0][2] += a0 * b2; acc[0][3] += a0 * b3;
            acc[1][0] += a1 * b0; acc[1][1] += a1 * b1; acc[1][2] += a1 * b2; acc[1][3] += a1 * b3;
        }
    }
#pragma unroll
    for (int i = 0; i < 2; i++)
#pragma unroll
        for (int j = 0; j < 4; j++) {
            int n = n0 + tx * 4 + j;
            if (n < O_) out[(size_t)(r0 + ty * 2 + i) * O_ + n] = acc[i][j] + lb[n];
        }
}

extern "C" void kernel_launch(void* const* d_in, const int* in_sizes, int n_in,
                              void* d_out, int out_size, void* d_ws, size_t ws_size,
                              hipStream_t stream) {
    const int* tok = (const int*)d_in[0];
    const float* emb = (const float*)d_in[1];
    const float* Wb = (const float*)d_in[2];
    const float* lw = (const float*)d_in[3];
    const float* lb = (const float*)d_in[4];
    float* out = (float*)d_out;

    char* ws = (char*)d_ws;
    unsigned short* Wbf = (unsigned short*)(ws);            // 131,072 B
    float*          fwp = (float*)(ws + 131072);            // 524,288 B

    hipLaunchKernelGGL(k_wt,   dim3(256),    dim3(256), 0, stream, Wb, Wbf);
    hipLaunchKernelGGL(k_attn, dim3(512),    dim3(512), 0, stream, tok, emb, Wbf, fwp);
    hipLaunchKernelGGL(k_out,  dim3(16, 16), dim3(256), 0, stream, fwp, lw, lb, out);
}